// Round 1
// baseline (257.029 us; speedup 1.0000x reference)
//
#include <hip/hip_runtime.h>
#include <stdint.h>
#include <stddef.h>

// Problem constants
#define B_ 4
#define L_ 8192
#define D_ 512
#define M_ (B_*L_)      // 32768 rows
#define N_ 1024         // Wg rows (512) ++ Wc rows (512), packed
#define K_ 512
#define CHUNK 128
#define NC (L_/CHUNK)   // 64 chunks per sequence

typedef _Float16 f16;
typedef f16 f16x4 __attribute__((ext_vector_type(4)));
typedef f16 f16x8 __attribute__((ext_vector_type(8)));
typedef float f32x4 __attribute__((ext_vector_type(4)));

// ---------------- async global->LDS (16B/lane) ----------------
__device__ __forceinline__ void async16(const void* g, void* l) {
  __builtin_amdgcn_global_load_lds(
      (const __attribute__((address_space(1))) uint32_t*)g,
      (__attribute__((address_space(3))) uint32_t*)l,
      16, 0, 0);
}

// ---------------- fp32 -> f16 conversion of x ----------------
__global__ __launch_bounds__(256) void cvt_x(const float* __restrict__ x,
                                             f16* __restrict__ xh) {
  int idx = (blockIdx.x * 256 + threadIdx.x) * 4;
  float4 v = *(const float4*)(x + idx);
  f16x4 o = {(f16)v.x, (f16)v.y, (f16)v.z, (f16)v.w};
  *(f16x4*)(xh + idx) = o;
}

// ---------------- pack Wg ++ Wc into f16 [1024][512] ----------------
__global__ __launch_bounds__(256) void pack_w(const float* __restrict__ Wg,
                                              const float* __restrict__ Wc,
                                              f16* __restrict__ wp) {
  int idx = (blockIdx.x * 256 + threadIdx.x) * 4;  // 0..524287
  const float* src = (idx < 262144) ? (Wg + idx) : (Wc + (idx - 262144));
  float4 v = *(const float4*)src;
  f16x4 o = {(f16)v.x, (f16)v.y, (f16)v.z, (f16)v.w};
  *(f16x4*)(wp + idx) = o;
}

// ---------------- fused GEMM + bias + activation ----------------
// Y[m][n] = sum_k Xh[m][k] * Wp[n][k]   (NT gemm)
// n < 512 : a = 1 - sigmoid(y + bg[n])        -> outA[m*512 + n]
// n >= 512: c = tanh(y + bc[n-512])           -> outC[m*512 + n-512]
__global__ __launch_bounds__(256) void gemm_act(
    const f16* __restrict__ Xh, const f16* __restrict__ Wp,
    const float* __restrict__ bg, const float* __restrict__ bc,
    float* __restrict__ outA, float* __restrict__ outC) {
  __shared__ __align__(16) f16 sA[128 * 32];
  __shared__ __align__(16) f16 sB[128 * 32];

  const int tid = threadIdx.x;
  const int bn = blockIdx.x & 7;     // 8 N-tiles
  const int bm = blockIdx.x >> 3;    // 256 M-tiles
  const int lane = tid & 63;
  const int w = tid >> 6;            // wave 0..3
  const int wm = w >> 1, wn = w & 1; // 2x2 wave grid over 128x128
  const int l15 = lane & 15, quad = lane >> 4;

  // staging: tid -> (row = tid>>2, 16B-piece = tid&3); LDS offset = tid*16B
  const int srow = tid >> 2;
  const int spc8 = (tid & 3) * 8;    // f16 element offset within row
  const f16* gA = Xh + (size_t)(bm * 128 + srow) * K_ + spc8;
  const f16* gB = Wp + (size_t)(bn * 128 + srow) * K_ + spc8;
  f16* lA = sA + tid * 8;
  f16* lB = sB + tid * 8;

  f32x4 acc[4][4] = {};

  for (int k0 = 0; k0 < K_; k0 += 32) {
    async16(gA + k0, lA);
    async16(gA + (size_t)64 * K_ + k0, lA + 64 * 32);
    async16(gB + k0, lB);
    async16(gB + (size_t)64 * K_ + k0, lB + 64 * 32);
    __syncthreads();  // drains vmcnt then barrier

    f16x8 af[4], bf[4];
#pragma unroll
    for (int i = 0; i < 4; i++)
      af[i] = *(const f16x8*)(sA + (wm * 64 + i * 16 + l15) * 32 + quad * 8);
#pragma unroll
    for (int j = 0; j < 4; j++)
      bf[j] = *(const f16x8*)(sB + (wn * 64 + j * 16 + l15) * 32 + quad * 8);
#pragma unroll
    for (int i = 0; i < 4; i++)
#pragma unroll
      for (int j = 0; j < 4; j++)
        acc[i][j] = __builtin_amdgcn_mfma_f32_16x16x32_f16(af[i], bf[j], acc[i][j], 0, 0, 0);
    __syncthreads();
  }

  // epilogue
  const bool isG = (bn < 4);                   // block-uniform
  float* outp = isG ? outA : outC;
  const float* bias = isG ? bg : bc;
  const int colbase = (bn & 3) * 128 + wn * 64 + l15;  // 0..511 within its half
#pragma unroll
  for (int j = 0; j < 4; j++) {
    const int col = colbase + j * 16;
    const float bv = bias[col];
#pragma unroll
    for (int i = 0; i < 4; i++) {
      const int mrow = bm * 128 + wm * 64 + i * 16 + quad * 4;
#pragma unroll
      for (int r = 0; r < 4; r++) {
        float y = acc[i][j][r] + bv;
        float val;
        if (isG) {
          val = 1.0f / (1.0f + __expf(y));     // a = 1 - sigmoid(y)
        } else {
          float yc = fminf(fmaxf(y, -15.0f), 15.0f);
          float t = __expf(2.0f * yc);
          val = (t - 1.0f) / (t + 1.0f);       // tanh(y)
        }
        outp[(size_t)(mrow + r) * 512 + col] = val;
      }
    }
  }
}

// ---------------- scan pass 1: per-chunk composite (P, Q) ----------------
// h_t = a_t h_{t-1} + (1-a_t) c_t ; chunk composite: h_out = P*h_in + Q
__global__ __launch_bounds__(512) void scan_local(
    const float* __restrict__ A, const float* __restrict__ C,
    float* __restrict__ cA, float* __restrict__ cB) {
  const int blk = blockIdx.x;        // = b*NC + ch ; global l0 = blk*CHUNK
  const int d = threadIdx.x;
  const size_t base = (size_t)blk * CHUNK * 512 + d;
  float P = 1.0f, Q = 0.0f;
#pragma unroll 8
  for (int t = 0; t < CHUNK; t++) {
    float a = A[base + (size_t)t * 512];
    float c = C[base + (size_t)t * 512];
    Q = fmaf(a, Q, (1.0f - a) * c);
    P *= a;
  }
  cA[blk * 512 + d] = P;
  cB[blk * 512 + d] = Q;
}

// ---------------- scan pass 2: prefix over chunks ----------------
__global__ __launch_bounds__(64) void scan_chunks(
    const float* __restrict__ cA, const float* __restrict__ cB,
    float* __restrict__ Hpre) {
  const int b = blockIdx.x >> 3;
  const int d = ((blockIdx.x & 7) << 6) + threadIdx.x;
  float h = 0.0f;
#pragma unroll 8
  for (int ch = 0; ch < NC; ch++) {
    const int idx = (b * NC + ch) * 512 + d;
    Hpre[idx] = h;                 // h entering chunk ch
    h = fmaf(cA[idx], h, cB[idx]);
  }
}

// ---------------- scan pass 3: apply prefix, write h in place ----------------
__global__ __launch_bounds__(512) void scan_apply(
    const float* __restrict__ A, float* __restrict__ OutC,
    const float* __restrict__ Hpre) {
  const int blk = blockIdx.x;
  const int d = threadIdx.x;
  const size_t base = (size_t)blk * CHUNK * 512 + d;
  float h = Hpre[blk * 512 + d];
#pragma unroll 8
  for (int t = 0; t < CHUNK; t++) {
    const size_t i = base + (size_t)t * 512;
    float a = A[i];
    float c = OutC[i];
    h = fmaf(a, h, (1.0f - a) * c);
    OutC[i] = h;
  }
}

// ---------------- launch ----------------
extern "C" void kernel_launch(void* const* d_in, const int* in_sizes, int n_in,
                              void* d_out, int out_size, void* d_ws, size_t ws_size,
                              hipStream_t stream) {
  const float* x  = (const float*)d_in[0];
  const float* Wg = (const float*)d_in[1];
  const float* bg = (const float*)d_in[2];
  const float* Wc = (const float*)d_in[3];
  const float* bc = (const float*)d_in[4];
  float* out = (float*)d_out;

  char* ws = (char*)d_ws;
  // workspace layout (bytes):
  //   [0, 32MB)           xh   f16 x
  //   [32MB, 33MB)        wp   f16 packed weights [1024][512]
  //   [33MB, 97MB)        wa   fp32 a = 1-g
  //   then cA, cB, Hpre (512KB each)  -> total ~98.5 MB
  f16*   xh = (f16*)(ws);
  f16*   wp = (f16*)(ws + 33554432);
  float* wa = (float*)(ws + 34603008);
  float* cA = (float*)(ws + 101711872);
  float* cB = (float*)(ws + 102236160);
  float* Hp = (float*)(ws + 102760448);

  cvt_x<<<M_ * D_ / (256 * 4), 256, 0, stream>>>(x, xh);          // 16384 blocks
  pack_w<<<N_ * K_ / (256 * 4), 256, 0, stream>>>(Wg, Wc, wp);    // 512 blocks
  gemm_act<<<(M_ / 128) * (N_ / 128), 256, 0, stream>>>(xh, wp, bg, bc, wa, out);
  scan_local<<<B_ * NC, 512, 0, stream>>>(wa, out, cA, cB);
  scan_chunks<<<32, 64, 0, stream>>>(cA, cB, Hp);
  scan_apply<<<B_ * NC, 512, 0, stream>>>(wa, out, Hp);
}

// Round 2
// 217.571 us; speedup vs baseline: 1.1814x; 1.1814x over previous
//
#include <hip/hip_runtime.h>
#include <stdint.h>
#include <stddef.h>

// Problem constants
#define B_ 4
#define L_ 8192
#define D_ 512
#define M_ (B_*L_)      // 32768 rows
#define K_ 512
#define CHUNK 64
#define NC (L_/CHUNK)   // 128 chunks per sequence

typedef _Float16 f16;
typedef f16 f16x2 __attribute__((ext_vector_type(2)));
typedef f16 f16x4 __attribute__((ext_vector_type(4)));
typedef f16 f16x8 __attribute__((ext_vector_type(8)));
typedef float f32x4 __attribute__((ext_vector_type(4)));

// ---------------- async global->LDS (16B/lane) ----------------
__device__ __forceinline__ void async16(const void* g, void* l) {
  __builtin_amdgcn_global_load_lds(
      (const __attribute__((address_space(1))) uint32_t*)g,
      (__attribute__((address_space(3))) uint32_t*)l,
      16, 0, 0);
}

// ---------------- fp32 -> f16 conversion of x ----------------
__global__ __launch_bounds__(256) void cvt_x(const float* __restrict__ x,
                                             f16* __restrict__ xh) {
  int idx = (blockIdx.x * 256 + threadIdx.x) * 4;
  float4 v = *(const float4*)(x + idx);
  f16x4 o = {(f16)v.x, (f16)v.y, (f16)v.z, (f16)v.w};
  *(f16x4*)(xh + idx) = o;
}

// ---------------- pack Wg ++ Wc into f16 [1024][512] ----------------
__global__ __launch_bounds__(256) void pack_w(const float* __restrict__ Wg,
                                              const float* __restrict__ Wc,
                                              f16* __restrict__ wp) {
  int idx = (blockIdx.x * 256 + threadIdx.x) * 4;  // 0..524287
  const float* src = (idx < 262144) ? (Wg + idx) : (Wc + (idx - 262144));
  float4 v = *(const float4*)src;
  f16x4 o = {(f16)v.x, (f16)v.y, (f16)v.z, (f16)v.w};
  *(f16x4*)(wp + idx) = o;
}

// ---------------- fused dual-B GEMM + activations, packed f16x2 out ------
// Per block: A-tile 128 rows (m), ONE 128-col tile, BOTH weight sets.
// yg = Xh·Wg^T + bg ; yc = Xh·Wc^T + bc
// a = 1 - sigmoid(yg); b = sigmoid(yg) * tanh(yc)
// AC[m*512 + col] = pack_f16x2(a, b)
__global__ __launch_bounds__(256, 2) void gemm_act(
    const f16* __restrict__ Xh, const f16* __restrict__ Wp,
    const float* __restrict__ bg, const float* __restrict__ bc,
    uint32_t* __restrict__ AC) {
  __shared__ __align__(16) f16 sA[128 * 32];
  __shared__ __align__(16) f16 sBg[128 * 32];
  __shared__ __align__(16) f16 sBc[128 * 32];

  const int tid = threadIdx.x;
  // XCD swizzle: same bm-tile's 4 col-blocks run consecutively on one XCD
  const int id = blockIdx.x;           // 0..1023
  const int xcd = id & 7;
  const int slot = id >> 3;            // 0..127
  const int g_ = xcd * 128 + slot;
  const int bm = g_ >> 2;              // 0..255
  const int bn = g_ & 3;               // 0..3 (128-col tiles)

  const int lane = tid & 63;
  const int w = tid >> 6;
  const int wm = w >> 1, wn = w & 1;   // 2x2 wave grid over 128x128
  const int l15 = lane & 15, quad = lane >> 4;

  // staging: tid -> (row = tid>>2, 16B piece = tid&3); covers 64 rows/round
  const int srow = tid >> 2;
  const int spc8 = (tid & 3) * 8;
  const f16* gA  = Xh + (size_t)(bm * 128 + srow) * K_ + spc8;
  const f16* gBg = Wp + (size_t)(bn * 128 + srow) * K_ + spc8;
  const f16* gBc = Wp + (size_t)(512 + bn * 128 + srow) * K_ + spc8;
  f16* lA  = sA  + tid * 8;
  f16* lBg = sBg + tid * 8;
  f16* lBc = sBc + tid * 8;

  f32x4 accG[4][4] = {};
  f32x4 accC[4][4] = {};

  for (int k0 = 0; k0 < K_; k0 += 32) {
    async16(gA + k0,  lA);
    async16(gA + (size_t)64 * K_ + k0,  lA  + 64 * 32);
    async16(gBg + k0, lBg);
    async16(gBg + (size_t)64 * K_ + k0, lBg + 64 * 32);
    async16(gBc + k0, lBc);
    async16(gBc + (size_t)64 * K_ + k0, lBc + 64 * 32);
    __syncthreads();  // drains vmcnt then barrier

    f16x8 af[4], bgf[4], bcf[4];
#pragma unroll
    for (int i = 0; i < 4; i++)
      af[i]  = *(const f16x8*)(sA  + (wm * 64 + i * 16 + l15) * 32 + quad * 8);
#pragma unroll
    for (int j = 0; j < 4; j++) {
      bgf[j] = *(const f16x8*)(sBg + (wn * 64 + j * 16 + l15) * 32 + quad * 8);
      bcf[j] = *(const f16x8*)(sBc + (wn * 64 + j * 16 + l15) * 32 + quad * 8);
    }
#pragma unroll
    for (int i = 0; i < 4; i++)
#pragma unroll
      for (int j = 0; j < 4; j++) {
        accG[i][j] = __builtin_amdgcn_mfma_f32_16x16x32_f16(af[i], bgf[j], accG[i][j], 0, 0, 0);
        accC[i][j] = __builtin_amdgcn_mfma_f32_16x16x32_f16(af[i], bcf[j], accC[i][j], 0, 0, 0);
      }
    __syncthreads();
  }

  // epilogue: fuse sigmoid/tanh, pack (a, b) as f16x2 -> one 4B store
#pragma unroll
  for (int j = 0; j < 4; j++) {
    const int col = bn * 128 + wn * 64 + j * 16 + l15;   // 0..511
    const float bgv = bg[col];
    const float bcv = bc[col];
#pragma unroll
    for (int i = 0; i < 4; i++) {
      const int mrow = bm * 128 + wm * 64 + i * 16 + quad * 4;
#pragma unroll
      for (int r = 0; r < 4; r++) {
        float yg = accG[i][j][r] + bgv;
        float gg = 1.0f / (1.0f + __expf(-yg));        // sigmoid
        float yc = accC[i][j][r] + bcv;
        yc = fminf(fmaxf(yc, -15.0f), 15.0f);
        float t = __expf(2.0f * yc);
        float cc = (t - 1.0f) / (t + 1.0f);            // tanh
        f16x2 p;
        p[0] = (f16)(1.0f - gg);                        // a
        p[1] = (f16)(gg * cc);                          // b
        *(f16x2*)&AC[(size_t)(mrow + r) * 512 + col] = p;
      }
    }
  }
}

// ---------------- scan pass 1: per-chunk composite (P, Q) ----------------
// h_t = a_t h_{t-1} + b_t ; chunk composite: h_out = P*h_in + Q
__global__ __launch_bounds__(512) void scan_local(
    const uint32_t* __restrict__ AC,
    float* __restrict__ cA, float* __restrict__ cB) {
  const int blk = blockIdx.x;          // 0..511 = b*NC + ch
  const int d = threadIdx.x;
  const size_t base = (size_t)blk * CHUNK * 512 + d;
  float P = 1.0f, Q = 0.0f;
#pragma unroll 8
  for (int t = 0; t < CHUNK; t++) {
    f16x2 v = *(const f16x2*)&AC[base + (size_t)t * 512];
    float a = (float)v[0], b = (float)v[1];
    Q = fmaf(a, Q, b);
    P *= a;
  }
  cA[blk * 512 + d] = P;
  cB[blk * 512 + d] = Q;
}

// ---------------- scan pass 2: prefix over chunks ----------------
__global__ __launch_bounds__(64) void scan_chunks(
    const float* __restrict__ cA, const float* __restrict__ cB,
    float* __restrict__ Hpre) {
  const int b = blockIdx.x >> 3;
  const int d = ((blockIdx.x & 7) << 6) + threadIdx.x;
  float h = 0.0f;
#pragma unroll 8
  for (int ch = 0; ch < NC; ch++) {
    const int idx = (b * NC + ch) * 512 + d;
    Hpre[idx] = h;                     // h entering chunk ch
    h = fmaf(cA[idx], h, cB[idx]);
  }
}

// ---------------- scan pass 3: apply prefix, write h ----------------
__global__ __launch_bounds__(512) void scan_apply(
    const uint32_t* __restrict__ AC, const float* __restrict__ Hpre,
    float* __restrict__ out) {
  const int blk = blockIdx.x;
  const int d = threadIdx.x;
  const size_t base = (size_t)blk * CHUNK * 512 + d;
  float h = Hpre[blk * 512 + d];
#pragma unroll 8
  for (int t = 0; t < CHUNK; t++) {
    const size_t i = base + (size_t)t * 512;
    f16x2 v = *(const f16x2*)&AC[i];
    h = fmaf((float)v[0], h, (float)v[1]);
    out[i] = h;
  }
}

// ---------------- launch ----------------
extern "C" void kernel_launch(void* const* d_in, const int* in_sizes, int n_in,
                              void* d_out, int out_size, void* d_ws, size_t ws_size,
                              hipStream_t stream) {
  const float* x  = (const float*)d_in[0];
  const float* Wg = (const float*)d_in[1];
  const float* bg = (const float*)d_in[2];
  const float* Wc = (const float*)d_in[3];
  const float* bc = (const float*)d_in[4];
  float* out = (float*)d_out;

  char* ws = (char*)d_ws;
  // workspace layout (bytes):
  //   [0, 32MB)      xh   f16 x
  //   [32MB, 33MB)   wp   f16 packed weights [1024][512]
  //   [33MB, 97MB)   AC   u32 packed (a,b) f16x2 [32768][512]
  //   [97MB..]       cA, cB, Hpre fp32 (1MB each)
  f16*      xh = (f16*)(ws);
  f16*      wp = (f16*)(ws + 33554432);
  uint32_t* AC = (uint32_t*)(ws + 34603008);
  float*    cA = (float*)(ws + 101711872);
  float*    cB = (float*)(ws + 102760448);
  float*    Hp = (float*)(ws + 103809024);

  cvt_x<<<M_ * D_ / (256 * 4), 256, 0, stream>>>(x, xh);          // 16384 blocks
  pack_w<<<2 * D_ * D_ / (256 * 4), 256, 0, stream>>>(Wg, Wc, wp);
  gemm_act<<<(M_ / 128) * 4, 256, 0, stream>>>(xh, wp, bg, bc, AC);  // 1024 blocks
  scan_local<<<B_ * NC, 512, 0, stream>>>(AC, cA, cB);               // 512 blocks
  scan_chunks<<<32, 64, 0, stream>>>(cA, cB, Hp);
  scan_apply<<<B_ * NC, 512, 0, stream>>>(AC, Hp, out);              // 512 blocks
}